// Round 12
// baseline (74.316 us; speedup 1.0000x reference)
//
#include <hip/hip_runtime.h>
#include <stdint.h>

// Bitnet int8 x int2 GEMM: C[M,N](i32) = A[M,K](i8) . W[N,K]^T
// Round 12: R11 skeleton (shared LDS ring, counted vmcnt(4) + barrier per
// iteration, stage-after-barrier) with 64x128 waves: block 128x128 = 2 wr
// x 2 K-halves (in-block K-split). Each A byte staged once AND read once
// (500 B LDS traffic per MFMA, 3x less than R11). LDS reduce at the end.

#define MM 1024
#define NN 11008
#define KK 4096
#define MTILES 8
#define NTILES 86
#define NBLOCKS (MTILES * NTILES)          // 688
#define STRIDE_A ((size_t)MTILES * 8192)   // A2 bytes per kstep (64)
#define STRIDE_B ((size_t)NTILES * 2048)   // B3 bytes per kstep

using i32x4  = __attribute__((ext_vector_type(4))) int;
using i32x16 = __attribute__((ext_vector_type(16))) int;

__device__ __forceinline__ int pack4(i32x4 v) {
    return (int)(((uint32_t)v[0] & 0xFFu) | (((uint32_t)v[1] & 0xFFu) << 8)
               | (((uint32_t)v[2] & 0xFFu) << 16) | (((uint32_t)v[3] & 0xFFu) << 24));
}

// Fused prepass (unchanged, proven absmax=0). Blocks [0,1024): A; rest: B.
// A2: [kstep][mtile][c]*16B, c = row32*128 + kk2*64 + lane;
//     data: row = mtile*128 + row32*32 + (lane&31), kbyte = kstep*64 + kk2*32
//     + (lane>>5)*16.
// B3: [kstep][ntile][half][lane]*16B, dword q = ni*2+kk2 = packed bytes of row
//     n = ntile*128+half*64+ni*32+(lane&31) at int32 off kstep*16+kk2*8+(lane>>5)*4.
__global__ __launch_bounds__(256) void prep_AB(const int* __restrict__ Asrc,
                                               const int* __restrict__ Bsrc,
                                               uint8_t* __restrict__ A2,
                                               uint8_t* __restrict__ B3) {
    if (blockIdx.x < 1024) {
        const int g = blockIdx.x * 256 + threadIdx.x;    // < 262144
        const int kstep = g >> 12;
        const int rem   = g & 4095;
        const int mtile = rem >> 9;
        const int c     = rem & 511;
        const int row32 = (c >> 7) & 3, kk2 = (c >> 6) & 1;
        const int lane  = c & 63;
        const int row   = mtile * 128 + row32 * 32 + (lane & 31);
        const int kbyte = kstep * 64 + kk2 * 32 + (lane >> 5) * 16;
        const i32x4* s4 = (const i32x4*)(Asrc + (size_t)row * KK + kbyte);
        i32x4 o;
#pragma unroll
        for (int q = 0; q < 4; ++q) o[q] = pack4(s4[q]);
        *(i32x4*)(A2 + (size_t)g * 16) = o;
    } else {
        const int t = (blockIdx.x - 1024) * 256 + threadIdx.x;   // < 704512
        const int n = t >> 6, kstep = t & 63;
        const int ntile = n >> 7, hf = (n >> 6) & 1, ni = (n >> 5) & 1, l31 = n & 31;
        const i32x4* s4 = (const i32x4*)(Bsrc + (size_t)n * (KK / 4) + kstep * 16);
        int w[4];                       // j = kk2*2 + h
#pragma unroll
        for (int j = 0; j < 4; ++j) w[j] = pack4(s4[j]);
        uint8_t* base = B3 + ((size_t)kstep * NTILES + ntile) * 2048 + hf * 1024;
        *(int2*)(base + l31 * 16 + ni * 8)        = make_int2(w[0], w[2]);  // h=0
        *(int2*)(base + (l31 + 32) * 16 + ni * 8) = make_int2(w[1], w[3]);  // h=1
    }
}

#define GLOAD_LDS16(g, l) __builtin_amdgcn_global_load_lds(                    \
        (const __attribute__((address_space(1))) uint32_t*)(g),                \
        (__attribute__((address_space(3))) uint32_t*)(l), 16, 0, 0)

#define MFMA_I8 __builtin_amdgcn_mfma_i32_32x32x32_i8

// Wave (wr,kh) stages its quarter (4 KB) of slot SL for its own K-half's
// dual-iter T2: global kstep = kh*32 + T2. Slot image: [kh][row32][kk2][lane].
#define STAGE2(SL, T2) do {                                                    \
    const uint8_t* s_ = gA + (size_t)(T2) * STRIDE_A;                          \
    uint8_t* l_ = &As[SL][kh * 8192 + wr * 4096];                              \
    GLOAD_LDS16(s_,        l_);                                                \
    GLOAD_LDS16(s_ + 1024, l_ + 1024);                                         \
    GLOAD_LDS16(s_ + 2048, l_ + 2048);                                         \
    GLOAD_LDS16(s_ + 3072, l_ + 3072);                                         \
} while (0)

// B pair (cols 0-63 and 64-127) for the wave's kstep kh*32 + T2.
#define BLOAD2(BI, T2) do {                                                    \
    c0[BI] = *(const i32x4*)(gB + (size_t)(T2) * STRIDE_B);                    \
    c1[BI] = *(const i32x4*)(gB + (size_t)(T2) * STRIDE_B + 1024);             \
} while (0)

// 16 MFMA: wave computes rows wr*64..+64, cols 0..128 of its K-half.
#define COMP2(SL, BI) do {                                                     \
    const uint8_t* ab_ = &As[SL][kh * 8192];                                   \
    i32x4 aA0_ = *(const i32x4*)(ab_ + (wr * 2 + 0) * 2048 + lane * 16);       \
    i32x4 aA1_ = *(const i32x4*)(ab_ + (wr * 2 + 0) * 2048 + 1024 + lane * 16);\
    i32x4 aB0_ = *(const i32x4*)(ab_ + (wr * 2 + 1) * 2048 + lane * 16);       \
    i32x4 aB1_ = *(const i32x4*)(ab_ + (wr * 2 + 1) * 2048 + 1024 + lane * 16);\
    _Pragma("unroll")                                                          \
    for (int kk2_ = 0; kk2_ < 2; ++kk2_) {                                     \
        const i32x4 am0_ = kk2_ ? aA1_ : aA0_;                                 \
        const i32x4 am1_ = kk2_ ? aB1_ : aB0_;                                 \
        _Pragma("unroll")                                                      \
        for (int nc_ = 0; nc_ < 4; ++nc_) {                                    \
            const uint32_t q_ = (uint32_t)((nc_ < 2 ? c0[BI] : c1[BI])[(nc_ & 1) * 2 + kk2_]); \
            i32x4 b_;                                                          \
            _Pragma("unroll")                                                  \
            for (int i_ = 0; i_ < 4; ++i_)                                     \
                b_[i_] = (int)((q_ >> (2 * i_)) & 0x03030303u);                \
            acc[0][nc_] = MFMA_I8(am0_, b_, acc[0][nc_], 0, 0, 0);             \
            acc[1][nc_] = MFMA_I8(am1_, b_, acc[1][nc_], 0, 0, 0);             \
        }                                                                      \
    }                                                                          \
} while (0)

// One dual-iteration: wait own loads (B(T) + stage(T) retired; in-order =>
// vmcnt(4) leaves only stage(T+1) outstanding) -> barrier (slot T globally
// ready; slot T-1 free) -> prefetch B(T+1) -> stage slot T+2 -> compute.
#define ITER2(T, SL, SLN, BI, BN, NW, DS, DB) do {                             \
    asm volatile("s_waitcnt vmcnt(" #NW ")" ::: "memory");                     \
    __builtin_amdgcn_s_barrier();                                              \
    __builtin_amdgcn_sched_barrier(0);                                         \
    if (DB) BLOAD2(BN, (T) + 1);                                               \
    if (DS) STAGE2(SLN, (T) + 2);                                              \
    COMP2(SL, BI);                                                             \
} while (0)

__global__ __launch_bounds__(256, 3) void bitnet_gemm(const uint8_t* __restrict__ A2,
                                                      const uint8_t* __restrict__ B3,
                                                      int* __restrict__ C) {
    const int tid  = threadIdx.x;
    const int lane = tid & 63, wave = tid >> 6;
    const int wr   = wave >> 1;          // row half (0..1)
    const int kh   = wave & 1;           // K half (0..1)
    const int l31  = lane & 31, h = lane >> 5;

    // bijective XCD swizzle (688 = 8*86), bm fastest within an XCD chunk.
    const int bid = blockIdx.x;
    const int l   = (bid & 7) * (NBLOCKS / 8) + (bid >> 3);
    const int bm  = l & 7;       // 128-row tile 0..7
    const int bn  = l >> 3;      // 128-col tile 0..85

    __shared__ __align__(16) uint8_t As[3][16384];   // 48 KiB ring

    const uint8_t* gA = A2 + (size_t)(kh * 32) * STRIDE_A + (size_t)bm * 8192
                      + wr * 4096 + lane * 16;
    const uint8_t* gB = B3 + (size_t)(kh * 32) * STRIDE_B + (size_t)bn * 2048
                      + lane * 16;

    i32x16 acc[2][4] = {};
    i32x4 c0[2], c1[2];

    // prologue: B(0), stage slots 0 and 1  (10 outstanding VMEM)
    BLOAD2(0, 0);
    STAGE2(0, 0);
    STAGE2(1, 1);

#pragma unroll 1
    for (int t = 0; t < 30; t += 6) {
        ITER2(t + 0, 0, 2, 0, 1, 4, 1, 1);
        ITER2(t + 1, 1, 0, 1, 0, 4, 1, 1);
        ITER2(t + 2, 2, 1, 0, 1, 4, 1, 1);
        ITER2(t + 3, 0, 2, 1, 0, 4, 1, 1);
        ITER2(t + 4, 1, 0, 0, 1, 4, 1, 1);
        ITER2(t + 5, 2, 1, 1, 0, 4, 1, 1);
    }
    // T=30: no stage (target 32 doesn't exist); still load B(31)
    ITER2(30, 0, 2, 0, 1, 4, 0, 1);
    // T=31: drain
    ITER2(31, 1, 0, 1, 0, 0, 0, 0);

    // K-half reduction + C write, one wr group at a time (32 KiB in ring).
    i32x4* red = (i32x4*)&As[0][0];
    const int brow = bm * 128 + wr * 64, bcol = bn * 128;
#pragma unroll
    for (int g = 0; g < 2; ++g) {
        __syncthreads();
        if (wr == g && kh == 1) {
#pragma unroll
            for (int mi = 0; mi < 2; ++mi)
#pragma unroll
                for (int nc = 0; nc < 4; ++nc) {
                    const i32x16 v = acc[mi][nc];
#pragma unroll
                    for (int q = 0; q < 4; ++q) {
                        i32x4 s;
                        s[0] = v[q * 4 + 0]; s[1] = v[q * 4 + 1];
                        s[2] = v[q * 4 + 2]; s[3] = v[q * 4 + 3];
                        red[((mi * 4 + nc) * 4 + q) * 64 + lane] = s;
                    }
                }
        }
        __syncthreads();
        if (wr == g && kh == 0) {
#pragma unroll
            for (int mi = 0; mi < 2; ++mi)
#pragma unroll
                for (int nc = 0; nc < 4; ++nc) {
                    i32x16 v = acc[mi][nc];
#pragma unroll
                    for (int q = 0; q < 4; ++q) {
                        const i32x4 r = red[((mi * 4 + nc) * 4 + q) * 64 + lane];
                        v[q * 4 + 0] += r[0]; v[q * 4 + 1] += r[1];
                        v[q * 4 + 2] += r[2]; v[q * 4 + 3] += r[3];
                    }
                    const int colg = bcol + nc * 32 + l31;
#pragma unroll
                    for (int r = 0; r < 16; ++r) {
                        const int rowin = (r & 3) + 8 * (r >> 2) + 4 * h;
                        const int rowg  = brow + mi * 32 + rowin;
                        C[(size_t)rowg * NN + colg] = v[r];
                    }
                }
        }
    }
}

extern "C" void kernel_launch(void* const* d_in, const int* in_sizes, int n_in,
                              void* d_out, int out_size, void* d_ws, size_t ws_size,
                              hipStream_t stream) {
    const int* A32 = (const int*)d_in[0];   // [M,K] int8 values in int32
    const int* B32 = (const int*)d_in[1];   // [N,K/4] packed bytes in int32
    int* C = (int*)d_out;                   // [M,N] int32

    uint8_t* A2 = (uint8_t*)d_ws;                      // 4 MiB
    uint8_t* B3 = A2 + (size_t)MM * KK;                // 10.75 MiB

    prep_AB<<<dim3(1024 + 2752), dim3(256), 0, stream>>>(A32, B32, A2, B3);
    bitnet_gemm<<<dim3(NBLOCKS), dim3(256), 0, stream>>>(A2, B3, C);
}

// Round 13
// 65.970 us; speedup vs baseline: 1.1265x; 1.1265x over previous
//
#include <hip/hip_runtime.h>
#include <stdint.h>

// Bitnet int8 x int2 GEMM: C[M,N](i32) = A[M,K](i8) . W[N,K]^T
// Round 13: R8 skeleton (128x128 block, 4 waves 2x2, shared LDS ring,
// counted vmcnt + barrier per K-step) with B STAGED IN LDS: per-block-step
// VMEM drops 16 KB -> 10 KB (L1 path 100% -> 63%), B fetched once per block.

#define MM 1024
#define NN 11008
#define KK 4096
#define MTILES 8
#define NTILES 86
#define NBLOCKS (MTILES * NTILES)          // 688
#define STRIDE_A ((size_t)MTILES * 8192)   // A2 bytes per kstep (64)
#define STRIDE_B ((size_t)NTILES * 2048)   // B3 bytes per kstep

using i32x4  = __attribute__((ext_vector_type(4))) int;
using i32x16 = __attribute__((ext_vector_type(16))) int;

__device__ __forceinline__ int pack4(i32x4 v) {
    return (int)(((uint32_t)v[0] & 0xFFu) | (((uint32_t)v[1] & 0xFFu) << 8)
               | (((uint32_t)v[2] & 0xFFu) << 16) | (((uint32_t)v[3] & 0xFFu) << 24));
}

// Fused prepass (unchanged, proven absmax=0). Blocks [0,1024): A; rest: B.
// A2: [kstep][mtile][c]*16B, c = row32*128 + kk2*64 + lane;
//     data: row = mtile*128 + row32*32 + (lane&31), kbyte = kstep*64 + kk2*32
//     + (lane>>5)*16.
// B3: [kstep][ntile][half][lane]*16B, dword q = ni*2+kk2 = packed bytes of row
//     n = ntile*128+half*64+ni*32+(lane&31) at int32 off kstep*16+kk2*8+(lane>>5)*4.
__global__ __launch_bounds__(256) void prep_AB(const int* __restrict__ Asrc,
                                               const int* __restrict__ Bsrc,
                                               uint8_t* __restrict__ A2,
                                               uint8_t* __restrict__ B3) {
    if (blockIdx.x < 1024) {
        const int g = blockIdx.x * 256 + threadIdx.x;    // < 262144
        const int kstep = g >> 12;
        const int rem   = g & 4095;
        const int mtile = rem >> 9;
        const int c     = rem & 511;
        const int row32 = (c >> 7) & 3, kk2 = (c >> 6) & 1;
        const int lane  = c & 63;
        const int row   = mtile * 128 + row32 * 32 + (lane & 31);
        const int kbyte = kstep * 64 + kk2 * 32 + (lane >> 5) * 16;
        const i32x4* s4 = (const i32x4*)(Asrc + (size_t)row * KK + kbyte);
        i32x4 o;
#pragma unroll
        for (int q = 0; q < 4; ++q) o[q] = pack4(s4[q]);
        *(i32x4*)(A2 + (size_t)g * 16) = o;
    } else {
        const int t = (blockIdx.x - 1024) * 256 + threadIdx.x;   // < 704512
        const int n = t >> 6, kstep = t & 63;
        const int ntile = n >> 7, hf = (n >> 6) & 1, ni = (n >> 5) & 1, l31 = n & 31;
        const i32x4* s4 = (const i32x4*)(Bsrc + (size_t)n * (KK / 4) + kstep * 16);
        int w[4];                       // j = kk2*2 + h
#pragma unroll
        for (int j = 0; j < 4; ++j) w[j] = pack4(s4[j]);
        uint8_t* base = B3 + ((size_t)kstep * NTILES + ntile) * 2048 + hf * 1024;
        *(int2*)(base + l31 * 16 + ni * 8)        = make_int2(w[0], w[2]);  // h=0
        *(int2*)(base + (l31 + 32) * 16 + ni * 8) = make_int2(w[1], w[3]);  // h=1
    }
}

#define GLOAD_LDS16(g, l) __builtin_amdgcn_global_load_lds(                    \
        (const __attribute__((address_space(1))) uint32_t*)(g),                \
        (__attribute__((address_space(3))) uint32_t*)(l), 16, 0, 0)

#define MFMA_I8 __builtin_amdgcn_mfma_i32_32x32x32_i8

// Stage K-step T into slot SL: A 8 KB (2 gload_lds/wave) + B 2 KB (waves 0,1).
// Slot layout: [0,8192) = A ([row32][kk2][lane]), [8192,10240) = B ([hf][lane]).
#define STAGE(SL, T) do {                                                      \
    const uint8_t* at_ = gA + (size_t)(T) * STRIDE_A;                          \
    uint8_t* l_ = &As[SL][0];                                                  \
    GLOAD_LDS16(at_,        l_ + wave * 1024);                                 \
    GLOAD_LDS16(at_ + 4096, l_ + 4096 + wave * 1024);                          \
    if (wave < 2)                                                              \
        GLOAD_LDS16(gBs + (size_t)(T) * STRIDE_B, l_ + 8192 + wave * 1024);    \
} while (0)

// 8 MFMA from slot SL: 4 A ds_read_b128 + 1 B ds_read_b128, decode in-reg.
#define COMP(SL) do {                                                          \
    const uint8_t* ab_ = &As[SL][0];                                           \
    i32x4 aA0_ = *(const i32x4*)(ab_ + (wr * 2 + 0) * 2048 + lane * 16);       \
    i32x4 aA1_ = *(const i32x4*)(ab_ + (wr * 2 + 0) * 2048 + 1024 + lane * 16);\
    i32x4 aB0_ = *(const i32x4*)(ab_ + (wr * 2 + 1) * 2048 + lane * 16);       \
    i32x4 aB1_ = *(const i32x4*)(ab_ + (wr * 2 + 1) * 2048 + 1024 + lane * 16);\
    const i32x4 bv_ = *(const i32x4*)(ab_ + 8192 + wc * 1024 + lane * 16);     \
    _Pragma("unroll")                                                          \
    for (int kk2_ = 0; kk2_ < 2; ++kk2_) {                                     \
        const uint32_t q0_ = (uint32_t)bv_[kk2_];                              \
        const uint32_t q1_ = (uint32_t)bv_[2 + kk2_];                          \
        i32x4 b0_, b1_;                                                        \
        _Pragma("unroll")                                                      \
        for (int i_ = 0; i_ < 4; ++i_) {                                       \
            b0_[i_] = (int)((q0_ >> (2 * i_)) & 0x03030303u);                  \
            b1_[i_] = (int)((q1_ >> (2 * i_)) & 0x03030303u);                  \
        }                                                                      \
        const i32x4 am0_ = kk2_ ? aA1_ : aA0_;                                 \
        const i32x4 am1_ = kk2_ ? aB1_ : aB0_;                                 \
        acc[0][0] = MFMA_I8(am0_, b0_, acc[0][0], 0, 0, 0);                    \
        acc[0][1] = MFMA_I8(am0_, b1_, acc[0][1], 0, 0, 0);                    \
        acc[1][0] = MFMA_I8(am1_, b0_, acc[1][0], 0, 0, 0);                    \
        acc[1][1] = MFMA_I8(am1_, b1_, acc[1][1], 0, 0, 0);                    \
    }                                                                          \
} while (0)

// Wave-dependent counted vmcnt: waves 0-1 issue 3 VMEM/iter, waves 2-3 issue
// 2. Steady state outstanding after wait = {stage(T+1), stage(T+2)}.
#define WAITN(N0, N2) do {                                                     \
    if (wave < 2) asm volatile("s_waitcnt vmcnt(" #N0 ")" ::: "memory");       \
    else          asm volatile("s_waitcnt vmcnt(" #N2 ")" ::: "memory");       \
} while (0)

// Iter T: wait own stage(T) retired -> barrier (slot T ready everywhere;
// slot (T-1)&3 free) -> stage slot (T+3)&3 -> compute slot T&3.
#define ITER(T, NW0, NW2, DS) do {                                             \
    WAITN(NW0, NW2);                                                           \
    __builtin_amdgcn_s_barrier();                                              \
    __builtin_amdgcn_sched_barrier(0);                                         \
    if (DS) STAGE(((T) + 3) & 3, (T) + 3);                                     \
    COMP((T) & 3);                                                             \
} while (0)

__global__ __launch_bounds__(256, 3) void bitnet_gemm(const uint8_t* __restrict__ A2,
                                                      const uint8_t* __restrict__ B3,
                                                      int* __restrict__ C) {
    const int tid  = threadIdx.x;
    const int lane = tid & 63, wave = tid >> 6;
    const int wr   = wave >> 1, wc = wave & 1;
    const int l31  = lane & 31, h = lane >> 5;

    // bijective XCD swizzle (688 = 8*86), bm fastest within an XCD chunk.
    const int bid = blockIdx.x;
    const int l   = (bid & 7) * (NBLOCKS / 8) + (bid >> 3);
    const int bm  = l & 7;       // 128-row tile 0..7
    const int bn  = l >> 3;      // 128-col tile 0..85

    __shared__ __align__(16) uint8_t As[4][10240];   // 40 KiB ring (A 8K + B 2K)

    const uint8_t* gA  = A2 + (size_t)bm * 8192 + tid * 16;
    const uint8_t* gBs = B3 + (size_t)bn * 2048 + wave * 1024 + lane * 16; // waves 0,1

    i32x16 acc[2][2] = {};

    // prologue: stage K-steps 0,1,2 (waves 0-1: 9 outstanding; waves 2-3: 6)
    STAGE(0, 0);
    STAGE(1, 1);
    STAGE(2, 2);

#pragma unroll 1
    for (int t = 0; t < 60; t += 4) {
        ITER(t + 0, 6, 4, 1);
        ITER(t + 1, 6, 4, 1);
        ITER(t + 2, 6, 4, 1);
        ITER(t + 3, 6, 4, 1);
    }
    // tail: last stage (K-step 63) issued at T=60
    ITER(60, 6, 4, 1);
    ITER(61, 6, 4, 0);
    ITER(62, 3, 2, 0);
    ITER(63, 0, 0, 0);

    // C write: col = lane&31, row = (r&3) + 8*(r>>2) + 4*(lane>>5)
    const int brow = bm * 128, bcol = bn * 128;
#pragma unroll
    for (int mi = 0; mi < 2; ++mi)
#pragma unroll
        for (int ni = 0; ni < 2; ++ni) {
            const int colg = bcol + wc * 64 + ni * 32 + l31;
#pragma unroll
            for (int r = 0; r < 16; ++r) {
                const int rowin = (r & 3) + 8 * (r >> 2) + 4 * h;
                const int rowg  = brow + wr * 64 + mi * 32 + rowin;
                C[(size_t)rowg * NN + colg] = acc[mi][ni][r];
            }
        }
}

extern "C" void kernel_launch(void* const* d_in, const int* in_sizes, int n_in,
                              void* d_out, int out_size, void* d_ws, size_t ws_size,
                              hipStream_t stream) {
    const int* A32 = (const int*)d_in[0];   // [M,K] int8 values in int32
    const int* B32 = (const int*)d_in[1];   // [N,K/4] packed bytes in int32
    int* C = (int*)d_out;                   // [M,N] int32

    uint8_t* A2 = (uint8_t*)d_ws;                      // 4 MiB
    uint8_t* B3 = A2 + (size_t)MM * KK;                // 10.75 MiB

    prep_AB<<<dim3(1024 + 2752), dim3(256), 0, stream>>>(A32, B32, A2, B3);
    bitnet_gemm<<<dim3(NBLOCKS), dim3(256), 0, stream>>>(A2, B3, C);
}

// Round 14
// 63.769 us; speedup vs baseline: 1.1654x; 1.0345x over previous
//
#include <hip/hip_runtime.h>
#include <stdint.h>

// Bitnet int8 x int2 GEMM: C[M,N](i32) = A[M,K](i8) . W[N,K]^T
// Round 14: producer-consumer wave specialization. 688 blocks x 5 waves:
// waves 0-3 = consumers (2x2, 64x64 tiles, ds_read+decode+MFMA ONLY, no
// VMEM, no vmcnt); wave 4 = producer (issues all 10 global_load_lds per
// K-step into a 4-slot x 10 KB ring, 3 ahead, counted vmcnt 20/10/0).
// Same prepass/layouts as R13 (proven absmax=0).

#define MM 1024
#define NN 11008
#define KK 4096
#define MTILES 8
#define NTILES 86
#define NBLOCKS (MTILES * NTILES)          // 688
#define STRIDE_A ((size_t)MTILES * 8192)   // A2 bytes per kstep (64)
#define STRIDE_B ((size_t)NTILES * 2048)   // B3 bytes per kstep

using i32x4  = __attribute__((ext_vector_type(4))) int;
using i32x16 = __attribute__((ext_vector_type(16))) int;

__device__ __forceinline__ int pack4(i32x4 v) {
    return (int)(((uint32_t)v[0] & 0xFFu) | (((uint32_t)v[1] & 0xFFu) << 8)
               | (((uint32_t)v[2] & 0xFFu) << 16) | (((uint32_t)v[3] & 0xFFu) << 24));
}

// Fused prepass (unchanged, proven). Blocks [0,1024): A; rest: B.
// A2: [kstep][mtile][c]*16B, c = row32*128 + kk2*64 + lane;
//     data: row = mtile*128 + row32*32 + (lane&31), kbyte = kstep*64 + kk2*32
//     + (lane>>5)*16.
// B3: [kstep][ntile][half][lane]*16B, dword q = ni*2+kk2 = packed bytes of row
//     n = ntile*128+half*64+ni*32+(lane&31) at int32 off kstep*16+kk2*8+(lane>>5)*4.
__global__ __launch_bounds__(256) void prep_AB(const int* __restrict__ Asrc,
                                               const int* __restrict__ Bsrc,
                                               uint8_t* __restrict__ A2,
                                               uint8_t* __restrict__ B3) {
    if (blockIdx.x < 1024) {
        const int g = blockIdx.x * 256 + threadIdx.x;    // < 262144
        const int kstep = g >> 12;
        const int rem   = g & 4095;
        const int mtile = rem >> 9;
        const int c     = rem & 511;
        const int row32 = (c >> 7) & 3, kk2 = (c >> 6) & 1;
        const int lane  = c & 63;
        const int row   = mtile * 128 + row32 * 32 + (lane & 31);
        const int kbyte = kstep * 64 + kk2 * 32 + (lane >> 5) * 16;
        const i32x4* s4 = (const i32x4*)(Asrc + (size_t)row * KK + kbyte);
        i32x4 o;
#pragma unroll
        for (int q = 0; q < 4; ++q) o[q] = pack4(s4[q]);
        *(i32x4*)(A2 + (size_t)g * 16) = o;
    } else {
        const int t = (blockIdx.x - 1024) * 256 + threadIdx.x;   // < 704512
        const int n = t >> 6, kstep = t & 63;
        const int ntile = n >> 7, hf = (n >> 6) & 1, ni = (n >> 5) & 1, l31 = n & 31;
        const i32x4* s4 = (const i32x4*)(Bsrc + (size_t)n * (KK / 4) + kstep * 16);
        int w[4];                       // j = kk2*2 + h
#pragma unroll
        for (int j = 0; j < 4; ++j) w[j] = pack4(s4[j]);
        uint8_t* base = B3 + ((size_t)kstep * NTILES + ntile) * 2048 + hf * 1024;
        *(int2*)(base + l31 * 16 + ni * 8)        = make_int2(w[0], w[2]);  // h=0
        *(int2*)(base + (l31 + 32) * 16 + ni * 8) = make_int2(w[1], w[3]);  // h=1
    }
}

#define GLOAD_LDS16(g, l) __builtin_amdgcn_global_load_lds(                    \
        (const __attribute__((address_space(1))) uint32_t*)(g),                \
        (__attribute__((address_space(3))) uint32_t*)(l), 16, 0, 0)

#define MFMA_I8 __builtin_amdgcn_mfma_i32_32x32x32_i8

// Producer: stage K-step T into slot T&3 (A 8 KB = 8 instrs, B 2 KB = 2).
// Slot layout: [0,8192) = A ([row32][kk2][lane]), [8192,10240) = B ([hf][lane]).
#define PSTAGE(T) do {                                                         \
    const uint8_t* at_ = gA + (size_t)(T) * STRIDE_A;                          \
    const uint8_t* bt_ = gB + (size_t)(T) * STRIDE_B;                          \
    uint8_t* l_ = &As[(T) & 3][0];                                             \
    GLOAD_LDS16(at_,        l_);                                               \
    GLOAD_LDS16(at_ + 1024, l_ + 1024);                                        \
    GLOAD_LDS16(at_ + 2048, l_ + 2048);                                        \
    GLOAD_LDS16(at_ + 3072, l_ + 3072);                                        \
    GLOAD_LDS16(at_ + 4096, l_ + 4096);                                        \
    GLOAD_LDS16(at_ + 5120, l_ + 5120);                                        \
    GLOAD_LDS16(at_ + 6144, l_ + 6144);                                        \
    GLOAD_LDS16(at_ + 7168, l_ + 7168);                                        \
    GLOAD_LDS16(bt_,        l_ + 8192);                                        \
    GLOAD_LDS16(bt_ + 1024, l_ + 9216);                                        \
} while (0)

// Consumer: 8 MFMA from slot T&3 (4 A + 1 B ds_read_b128, decode in-reg).
#define COMP(T) do {                                                           \
    const uint8_t* ab_ = &As[(T) & 3][0];                                      \
    i32x4 aA0_ = *(const i32x4*)(ab_ + (wr * 2 + 0) * 2048 + lane * 16);       \
    i32x4 aA1_ = *(const i32x4*)(ab_ + (wr * 2 + 0) * 2048 + 1024 + lane * 16);\
    i32x4 aB0_ = *(const i32x4*)(ab_ + (wr * 2 + 1) * 2048 + lane * 16);       \
    i32x4 aB1_ = *(const i32x4*)(ab_ + (wr * 2 + 1) * 2048 + 1024 + lane * 16);\
    const i32x4 bv_ = *(const i32x4*)(ab_ + 8192 + wc * 1024 + lane * 16);     \
    _Pragma("unroll")                                                          \
    for (int kk2_ = 0; kk2_ < 2; ++kk2_) {                                     \
        const uint32_t q0_ = (uint32_t)bv_[kk2_];                              \
        const uint32_t q1_ = (uint32_t)bv_[2 + kk2_];                          \
        i32x4 b0_, b1_;                                                        \
        _Pragma("unroll")                                                      \
        for (int i_ = 0; i_ < 4; ++i_) {                                       \
            b0_[i_] = (int)((q0_ >> (2 * i_)) & 0x03030303u);                  \
            b1_[i_] = (int)((q1_ >> (2 * i_)) & 0x03030303u);                  \
        }                                                                      \
        const i32x4 am0_ = kk2_ ? aA1_ : aA0_;                                 \
        const i32x4 am1_ = kk2_ ? aB1_ : aB0_;                                 \
        acc[0][0] = MFMA_I8(am0_, b0_, acc[0][0], 0, 0, 0);                    \
        acc[0][1] = MFMA_I8(am0_, b1_, acc[0][1], 0, 0, 0);                    \
        acc[1][0] = MFMA_I8(am1_, b0_, acc[1][0], 0, 0, 0);                    \
        acc[1][1] = MFMA_I8(am1_, b1_, acc[1][1], 0, 0, 0);                    \
    }                                                                          \
} while (0)

#define PWAIT(N) asm volatile("s_waitcnt vmcnt(" #N ")" ::: "memory")

__global__ __launch_bounds__(320, 3) void bitnet_gemm(const uint8_t* __restrict__ A2,
                                                      const uint8_t* __restrict__ B3,
                                                      int* __restrict__ C) {
    const int tid  = threadIdx.x;
    const int lane = tid & 63, wave = tid >> 6;   // waves 0-3 consume, 4 produces
    const int wr   = (wave >> 1) & 1, wc = wave & 1;
    const int l31  = lane & 31, h = lane >> 5;

    // bijective XCD swizzle (688 = 8*86), bm fastest within an XCD chunk.
    const int bid = blockIdx.x;
    const int l   = (bid & 7) * (NBLOCKS / 8) + (bid >> 3);
    const int bm  = l & 7;       // 128-row tile 0..7
    const int bn  = l >> 3;      // 128-col tile 0..85

    __shared__ __align__(16) uint8_t As[4][10240];   // 40 KiB ring

    if (wave == 4) {
        // ---------------- producer ----------------
        const uint8_t* gA = A2 + (size_t)bm * 8192 + lane * 16;
        const uint8_t* gB = B3 + (size_t)bn * 2048 + lane * 16;

        PSTAGE(0); PSTAGE(1); PSTAGE(2);   // 30 outstanding
        PWAIT(20);                         // slot 0 resident
#pragma unroll 1
        for (int t = 0; t < 60; t += 4) {
            // steady state: barrier B_T; issue stage(T+3); wait -> slot T+1
            __builtin_amdgcn_s_barrier(); PSTAGE(t + 3); PWAIT(20);
            __builtin_amdgcn_s_barrier(); PSTAGE(t + 4); PWAIT(20);
            __builtin_amdgcn_s_barrier(); PSTAGE(t + 5); PWAIT(20);
            __builtin_amdgcn_s_barrier(); PSTAGE(t + 6); PWAIT(20);
        }
        __builtin_amdgcn_s_barrier(); PSTAGE(63); PWAIT(20);  // T=60
        __builtin_amdgcn_s_barrier(); PWAIT(10);              // T=61 -> slot 62
        __builtin_amdgcn_s_barrier(); PWAIT(0);               // T=62 -> slot 63
        __builtin_amdgcn_s_barrier();                         // T=63
        return;
    }

    // ---------------- consumers ----------------
    i32x16 acc[2][2] = {};

#pragma unroll 1
    for (int t = 0; t < 64; t += 4) {
        __builtin_amdgcn_s_barrier();
        __builtin_amdgcn_sched_barrier(0);
        COMP(t + 0);
        __builtin_amdgcn_s_barrier();
        __builtin_amdgcn_sched_barrier(0);
        COMP(t + 1);
        __builtin_amdgcn_s_barrier();
        __builtin_amdgcn_sched_barrier(0);
        COMP(t + 2);
        __builtin_amdgcn_s_barrier();
        __builtin_amdgcn_sched_barrier(0);
        COMP(t + 3);
    }

    // C write: col = lane&31, row = (r&3) + 8*(r>>2) + 4*(lane>>5)
    const int brow = bm * 128, bcol = bn * 128;
#pragma unroll
    for (int mi = 0; mi < 2; ++mi)
#pragma unroll
        for (int ni = 0; ni < 2; ++ni) {
            const int colg = bcol + wc * 64 + ni * 32 + l31;
#pragma unroll
            for (int r = 0; r < 16; ++r) {
                const int rowin = (r & 3) + 8 * (r >> 2) + 4 * h;
                const int rowg  = brow + wr * 64 + mi * 32 + rowin;
                C[(size_t)rowg * NN + colg] = acc[mi][ni][r];
            }
        }
}

extern "C" void kernel_launch(void* const* d_in, const int* in_sizes, int n_in,
                              void* d_out, int out_size, void* d_ws, size_t ws_size,
                              hipStream_t stream) {
    const int* A32 = (const int*)d_in[0];   // [M,K] int8 values in int32
    const int* B32 = (const int*)d_in[1];   // [N,K/4] packed bytes in int32
    int* C = (int*)d_out;                   // [M,N] int32

    uint8_t* A2 = (uint8_t*)d_ws;                      // 4 MiB
    uint8_t* B3 = A2 + (size_t)MM * KK;                // 10.75 MiB

    prep_AB<<<dim3(1024 + 2752), dim3(256), 0, stream>>>(A32, B32, A2, B3);
    bitnet_gemm<<<dim3(NBLOCKS), dim3(320), 0, stream>>>(A2, B3, C);
}